// Round 8
// baseline (400.455 us; speedup 1.0000x reference)
//
#include <hip/hip_runtime.h>
#include <hip/hip_bf16.h>
#include <hip/hip_cooperative_groups.h>

namespace cg = cooperative_groups;

#define D_MODEL 1024
#define D_INNER 2048
#define DT_RANK 64
#define D_STATE 16
#define LSEQ    2048
#define CHUNK   32
#define NCHUNK  (LSEQ / CHUNK)       // 64
#define DN      (D_INNER * D_STATE)  // 32768
#define KSPL_O  4                    // split-K for out-proj
#define KSPL_X  16                   // split-K for x-proj

typedef __attribute__((ext_vector_type(8))) short  short8;
typedef __attribute__((ext_vector_type(4))) float  float4v;
typedef __hip_bfloat16 bf16;

static __device__ __forceinline__ float b2f(bf16 v) { return __bfloat162float(v); }
static __device__ __forceinline__ bf16  f2b(float v) { return __float2bfloat16(v); }
static __device__ __forceinline__ float us2f(unsigned short u) {
    union { unsigned int i; float f; } cc; cc.i = ((unsigned int)u) << 16; return cc.f;
}
static __device__ __forceinline__ unsigned short f2us(float v) {
    return __bfloat16_as_ushort(__float2bfloat16(v));
}

#define GLOAD_LDS16(g, l)                                                          \
    __builtin_amdgcn_global_load_lds((const __attribute__((address_space(1))) void*)(g), \
                                     (__attribute__((address_space(3))) void*)(l), 16, 0, 0)

// ---------------------- fused prep: RMSNorm (blocks 0..2047) + weight casts ----
#define N1 (2 * D_INNER * D_MODEL)   // W_in
#define N2 (D_MODEL * D_INNER)       // W_out
#define N3 (96 * D_INNER)            // W_xproj
#define N4 (D_INNER * DT_RANK)       // W_dt
#define NCAST4 ((N1 + N2 + N3 + N4) / 4)
__global__ __launch_bounds__(256)
void prep_kernel(const float* __restrict__ x, const float* __restrict__ nw,
                 bf16* __restrict__ xn,
                 const float* __restrict__ w_in, const float* __restrict__ w_out,
                 const float* __restrict__ w_xp, const float* __restrict__ w_dt,
                 bf16* __restrict__ o_in, bf16* __restrict__ o_out,
                 bf16* __restrict__ o_xp, bf16* __restrict__ o_dt) {
    int t = threadIdx.x;
    if (blockIdx.x < LSEQ) {   // RMSNorm row
        int l = blockIdx.x;
        float4v v = ((const float4v*)(x + (size_t)l * D_MODEL))[t];
        float ssq = v[0]*v[0] + v[1]*v[1] + v[2]*v[2] + v[3]*v[3];
        for (int o = 32; o > 0; o >>= 1) ssq += __shfl_down(ssq, o);
        __shared__ float part[4];
        int lane = t & 63, wid = t >> 6;
        if (lane == 0) part[wid] = ssq;
        __syncthreads();
        float tot = part[0] + part[1] + part[2] + part[3];
        float sc = rsqrtf(tot * (1.0f / D_MODEL) + 1e-5f);
        float4v nv = ((const float4v*)nw)[t];
        bf16* op = xn + (size_t)l * D_MODEL + t * 4;
        op[0] = f2b(v[0] * sc * nv[0]);
        op[1] = f2b(v[1] * sc * nv[1]);
        op[2] = f2b(v[2] * sc * nv[2]);
        op[3] = f2b(v[3] * sc * nv[3]);
        return;
    }
    int i4 = (blockIdx.x - LSEQ) * 256 + t;
    if (i4 >= NCAST4) return;
    const float* src; bf16* dst; int base;
    if (i4 < N1 / 4)                { src = w_in;  dst = o_in;  base = 0; }
    else if (i4 < (N1 + N2) / 4)    { src = w_out; dst = o_out; base = N1 / 4; }
    else if (i4 < (N1+N2+N3) / 4)   { src = w_xp;  dst = o_xp;  base = (N1+N2) / 4; }
    else                            { src = w_dt;  dst = o_dt;  base = (N1+N2+N3) / 4; }
    int j = i4 - base;
    float4v v = ((const float4v*)src)[j];
    bf16* o = dst + j * 4;
    o[0] = f2b(v[0]); o[1] = f2b(v[1]); o[2] = f2b(v[2]); o[3] = f2b(v[3]);
}

// ---- fast NT GEMM: 512 threads / 8 waves, wave tile 32x64, BK=64, dbuf LDS ---
// C[M,N] = A[M,K]*B[N,K]^T. Tiles 128x128. kLen%64==0.
// LDS physical 16B-chunk = logical chunk ^ (row&7) -> conflict-free stage+read.
// XCD-aware block swizzle: cluster tiles sharing A/B slabs onto one XCD's L2.
// MODE 0: outB = bf16(acc)                       (xz)
// MODE 2: outB = bf16(softplus(acc+bias[n]))     (delta)
// MODE 4: outF[z-slice] = acc                    (split-K partials)
template <int MODE>
__global__ __launch_bounds__(512)
void gemm_fast(const bf16* __restrict__ Ab, const bf16* __restrict__ Bb,
               int M, int N, int K, int kLen,
               float* __restrict__ outF, bf16* __restrict__ outB,
               const float* __restrict__ bias) {
    __shared__ short As[2][128 * 64];   // 16 KB per buffer
    __shared__ short Bs[2][128 * 64];
    const short* Ap = (const short*)Ab;
    const short* Bp = (const short*)Bb;

    int t = threadIdx.x;
    int lane = t & 63, wid = t >> 6;            // 8 waves

    // ---- XCD swizzle (assignment heuristic: linear block id % 8 -> XCD) ----
    int bx, by, bz;
    if (MODE == 0) {            // grid 32x16x1: 8 windows of 8bx x 8by (~4MB/XCD)
        int id = blockIdx.y * gridDim.x + blockIdx.x;
        int xcd = id & 7, slot = id >> 3;       // slot 0..63
        bx = (xcd & 3) * 8 + (slot & 7);
        by = (xcd >> 2) * 8 + (slot >> 3);
        bz = 0;
    } else if (MODE == 4) {     // z-split grids: per-XCD (by,z) windows
        int id = (blockIdx.z * gridDim.y + blockIdx.y) * gridDim.x + blockIdx.x;
        int xcd = id & 7, slot = id >> 3;
        bx = slot % gridDim.x;
        int byz = xcd * ((gridDim.y * gridDim.z) / 8) + slot / gridDim.x;
        by = byz % gridDim.y;
        bz = byz / gridDim.y;
    } else {
        bx = blockIdx.x; by = blockIdx.y; bz = blockIdx.z;
    }
    int mBase = by * 128, nBase = bx * 128;
    int kBase = bz * kLen;
    int wm = 32 * (wid >> 1), wn = 64 * (wid & 1);   // wave tile 32x64
    int lr = lane & 15, quad = lane >> 4;

    // staging: wave wid owns rows [16*wid, 16*wid+16); 2 instrs of 8 rows each.
    int srow = 16 * wid + (lane >> 3);
    int cg2 = (lane & 7) ^ (lane >> 3);         // global chunk for phys chunk lane&7
    const short* gA = Ap + (size_t)(mBase + srow) * K + cg2 * 8;
    const short* gB = Bp + (size_t)(nBase + srow) * K + cg2 * 8;

    float4v acc[2][4] = {};

    // prologue: stage first K-slab into buf 0
    #pragma unroll
    for (int g = 0; g < 2; ++g) {
        GLOAD_LDS16(gA + (size_t)g * 8 * K + kBase, &As[0][(16 * wid + g * 8) * 64]);
        GLOAD_LDS16(gB + (size_t)g * 8 * K + kBase, &Bs[0][(16 * wid + g * 8) * 64]);
    }

    int p = 0;
    for (int kt = kBase; kt < kBase + kLen; kt += 64, p ^= 1) {
        __syncthreads();   // drains buf[p] loads; all waves past buf[p^1] reads
        if (kt + 64 < kBase + kLen) {
            int kn = kt + 64, q = p ^ 1;
            #pragma unroll
            for (int g = 0; g < 2; ++g) {
                GLOAD_LDS16(gA + (size_t)g * 8 * K + kn, &As[q][(16 * wid + g * 8) * 64]);
                GLOAD_LDS16(gB + (size_t)g * 8 * K + kn, &Bs[q][(16 * wid + g * 8) * 64]);
            }
        }
        #pragma unroll
        for (int s = 0; s < 2; ++s) {
            short8 af[2], bfr[4];
            #pragma unroll
            for (int i = 0; i < 2; ++i) {
                int row = wm + i * 16 + lr;
                af[i] = *(const short8*)&As[p][row * 64 + (((s * 4 + quad) ^ (lr & 7)) * 8)];
            }
            #pragma unroll
            for (int j = 0; j < 4; ++j) {
                int row = wn + j * 16 + lr;
                bfr[j] = *(const short8*)&Bs[p][row * 64 + (((s * 4 + quad) ^ (lr & 7)) * 8)];
            }
            #pragma unroll
            for (int i = 0; i < 2; ++i)
                #pragma unroll
                for (int j = 0; j < 4; ++j)
                    acc[i][j] = __builtin_amdgcn_mfma_f32_16x16x32_bf16(af[i], bfr[j], acc[i][j], 0, 0, 0);
        }
    }

    #pragma unroll
    for (int i = 0; i < 2; ++i) {
        #pragma unroll
        for (int j = 0; j < 4; ++j) {
            #pragma unroll
            for (int r = 0; r < 4; ++r) {
                int gm = mBase + wm + i * 16 + quad * 4 + r;
                int gn = nBase + wn + j * 16 + lr;
                float v = acc[i][j][r];
                if (MODE == 0) {
                    outB[(size_t)gm * N + gn] = f2b(v);
                } else if (MODE == 2) {
                    v += bias[gn];
                    v = (v > 20.0f) ? v : log1pf(__expf(v));
                    outB[(size_t)gm * N + gn] = f2b(v);
                } else {  // MODE 4: split-K partials
                    outF[((size_t)bz * M + gm) * N + gn] = v;
                }
            }
        }
    }
}

// --------------- x_proj reduce: dbc = sum_z part, + dt bf16 cast (fused) ------
__global__ __launch_bounds__(128)
void reduce_xproj(const float* __restrict__ part, float* __restrict__ dbc,
                  bf16* __restrict__ dtb) {
    int m = blockIdx.x, j = threadIdx.x;
    if (j >= 96) return;
    float v = 0.0f;
    #pragma unroll
    for (int z = 0; z < KSPL_X; ++z)
        v += part[((size_t)z * LSEQ + m) * 128 + j];
    dbc[(size_t)m * 96 + j] = v;
    if (j < DT_RANK) dtb[(size_t)m * DT_RANK + j] = f2b(v);
}

// --------------- out reduce: d_out = sum_z part + x (residual fused) ----------
__global__ __launch_bounds__(256)
void reduce_out(const float* __restrict__ part, const float* __restrict__ x,
                float* __restrict__ out) {
    int i = blockIdx.x * 256 + threadIdx.x;   // float4 over M*N/4
    const int MN4 = LSEQ * D_MODEL / 4;
    float4v a = ((const float4v*)part)[i];
    #pragma unroll
    for (int z = 1; z < KSPL_O; ++z) {
        float4v b = ((const float4v*)part)[(size_t)z * MN4 + i];
        a[0] += b[0]; a[1] += b[1]; a[2] += b[2]; a[3] += b[3];
    }
    float4v xv = ((const float4v*)x)[i];
    a[0] += xv[0]; a[1] += xv[1]; a[2] += xv[2]; a[3] += xv[3];
    ((float4v*)out)[i] = a;
}

// ------------- depthwise causal conv+SiLU, 2 channels x 4 timesteps/thread ----
__global__ void conv_kernel(const bf16* __restrict__ xz, const float* __restrict__ cw,
                            const float* __restrict__ cb, bf16* __restrict__ xsb) {
    int idx = blockIdx.x * 256 + threadIdx.x;   // over (LSEQ/4)*(D_INNER/2)
    int c = (idx & (D_INNER / 2 - 1)) * 2;
    int l0 = (idx >> 10) * 4;
    float4v wA = ((const float4v*)cw)[c];       // cw row c: 4 floats
    float4v wB = ((const float4v*)cw)[c + 1];
    float bA = cb[c], bB = cb[c + 1];
    const unsigned int* col = (const unsigned int*)((const unsigned short*)xz + c);
    float vA[7], vB[7];
    #pragma unroll
    for (int j = 0; j < 7; ++j) {
        int l = l0 - 3 + j;
        if (l >= 0) {
            unsigned int u = col[(size_t)l * D_INNER];   // 2 bf16 = 4B, stride 2*D_INNER shorts
            vA[j] = us2f((unsigned short)(u & 0xffff));
            vB[j] = us2f((unsigned short)(u >> 16));
        } else { vA[j] = 0.0f; vB[j] = 0.0f; }
    }
    #pragma unroll
    for (int j = 0; j < 4; ++j) {
        float aA = bA + vA[j]*wA[0] + vA[j+1]*wA[1] + vA[j+2]*wA[2] + vA[j+3]*wA[3];
        float aB = bB + vB[j]*wB[0] + vB[j+1]*wB[1] + vB[j+2]*wB[2] + vB[j+3]*wB[3];
        float sA = aA * (1.0f / (1.0f + __expf(-aA)));
        float sB = aB * (1.0f / (1.0f + __expf(-aB)));
        unsigned int o = (unsigned int)f2us(sA) | ((unsigned int)f2us(sB) << 16);
        *(unsigned int*)((unsigned short*)xsb + (size_t)(l0 + j) * D_INNER + c) = o;
    }
}

// ---------------- cooperative fused scan: pass0 + chunk-compose + pass1 -------
// grid (D_INNER/256, NCHUNK) x 256 threads; thread = (d, chunk c).
__global__ __launch_bounds__(256)
void scan_fused(const bf16* __restrict__ delta, const bf16* __restrict__ xsb,
                const float* __restrict__ dbc, const bf16* __restrict__ xz,
                const float* __restrict__ A_log, const float* __restrict__ Dw,
                float* __restrict__ P, float* __restrict__ S,
                float* __restrict__ Hinit, bf16* __restrict__ yg) {
    cg::grid_group grid = cg::this_grid();
    __shared__ float bc[CHUNK][32];   // [l][B(16)|C(16)], staged once, used twice
    int t = threadIdx.x;
    int d = blockIdx.x * 256 + t;
    int c = blockIdx.y;
    int l0 = c * CHUNK;

    {
        int row = t >> 3, col = (t & 7) * 4;
        *(float4v*)&bc[row][col] = *(const float4v*)&dbc[(size_t)(l0 + row) * 96 + 64 + col];
    }
    __syncthreads();

    float A[16], h[16], pr[16];
    #pragma unroll
    for (int n = 0; n < 16; ++n) A[n] = -__expf(A_log[(size_t)d * 16 + n]);

    // ---- pass 0: local scan from 0, accumulate decay product ----
    #pragma unroll
    for (int n = 0; n < 16; ++n) { h[n] = 0.0f; pr[n] = 1.0f; }
    for (int i = 0; i < CHUNK; ++i) {
        int l = l0 + i;
        float dv = b2f(delta[(size_t)l * D_INNER + d]);
        float xv = b2f(xsb[(size_t)l * D_INNER + d]);
        float u = dv * xv;
        #pragma unroll
        for (int n = 0; n < 16; ++n) {
            float a = __expf(dv * A[n]);
            h[n] = fmaf(a, h[n], bc[i][n] * u);
            pr[n] *= a;
        }
    }
    #pragma unroll
    for (int n = 0; n < 16; n += 4) {
        *(float4v*)&P[(size_t)c * DN + (size_t)d * 16 + n] = *(float4v*)&pr[n];
        *(float4v*)&S[(size_t)c * DN + (size_t)d * 16 + n] = *(float4v*)&h[n];
    }

    grid.sync();

    // ---- mid: sequential compose over chunks (1/4 of threads active) ----
    int gid = (blockIdx.y * gridDim.x + blockIdx.x) * 256 + t;
    if (gid < DN) {
        float hh = 0.0f;
        for (int c0 = 0; c0 < NCHUNK; c0 += 8) {
            float pp[8], ss[8];
            #pragma unroll
            for (int j = 0; j < 8; ++j) {
                pp[j] = P[(size_t)(c0 + j) * DN + gid];
                ss[j] = S[(size_t)(c0 + j) * DN + gid];
            }
            #pragma unroll
            for (int j = 0; j < 8; ++j) {
                Hinit[(size_t)(c0 + j) * DN + gid] = hh;
                hh = fmaf(pp[j], hh, ss[j]);
            }
        }
    }

    grid.sync();

    // ---- pass 1: seeded re-scan, emit gated output ----
    #pragma unroll
    for (int n = 0; n < 16; n += 4)
        *(float4v*)&h[n] = *(const float4v*)&Hinit[(size_t)c * DN + (size_t)d * 16 + n];
    float Dd = Dw[d];
    for (int i = 0; i < CHUNK; ++i) {
        int l = l0 + i;
        float dv = b2f(delta[(size_t)l * D_INNER + d]);
        float xv = b2f(xsb[(size_t)l * D_INNER + d]);
        float u = dv * xv;
        float y = xv * Dd;
        #pragma unroll
        for (int n = 0; n < 16; ++n) {
            float a = __expf(dv * A[n]);
            h[n] = fmaf(a, h[n], bc[i][n] * u);
            y = fmaf(h[n], bc[i][16 + n], y);
        }
        float r = b2f(xz[(size_t)l * (2 * D_INNER) + D_INNER + d]);
        float g = r * (1.0f / (1.0f + __expf(-r)));
        yg[(size_t)l * D_INNER + d] = f2b(y * g);
    }
}

// -------------------------------------------------------------- launcher ----
extern "C" void kernel_launch(void* const* d_in, const int* in_sizes, int n_in,
                              void* d_out, int out_size, void* d_ws, size_t ws_size,
                              hipStream_t stream) {
    const float* x       = (const float*)d_in[0];
    const float* W_in    = (const float*)d_in[1];
    const float* conv_w  = (const float*)d_in[2];
    const float* conv_b  = (const float*)d_in[3];
    const float* W_xproj = (const float*)d_in[4];
    const float* W_dt    = (const float*)d_in[5];
    const float* b_dt    = (const float*)d_in[6];
    const float* A_log   = (const float*)d_in[7];
    const float* Dw      = (const float*)d_in[8];
    const float* W_out   = (const float*)d_in[9];
    const float* norm_w  = (const float*)d_in[10];

    char* w = (char*)d_ws;
    bf16* W_in_b    = (bf16*)w; w += (size_t)2 * D_INNER * D_MODEL * 2;   // 8 MB
    bf16* W_out_b   = (bf16*)w; w += (size_t)D_MODEL * D_INNER * 2;       // 4 MB
    bf16* W_xproj_b = (bf16*)w; w += (size_t)128 * D_INNER * 2;           // 512 KB (rows 96..127 pad)
    bf16* W_dt_b    = (bf16*)w; w += (size_t)D_INNER * DT_RANK * 2;       // 256 KB
    char* reuse0 = w;   // aliased by out_part after scan
    bf16* xn        = (bf16*)w; w += (size_t)LSEQ * D_MODEL * 2;          // 4 MB
    bf16* xz        = (bf16*)w; w += (size_t)LSEQ * 2 * D_INNER * 2;      // 16 MB
    bf16* xsb       = (bf16*)w; w += (size_t)LSEQ * D_INNER * 2;          // 8 MB
    bf16* delta     = (bf16*)w; w += (size_t)LSEQ * D_INNER * 2;          // 8 MB  (36 MB pool)
    float* dbc      = (float*)w; w += (size_t)LSEQ * 96 * 4;              // 768 KB
    bf16* dtb       = (bf16*)w; w += (size_t)LSEQ * DT_RANK * 2;          // 256 KB
    bf16* yg        = (bf16*)w; w += (size_t)LSEQ * D_INNER * 2;          // 8 MB
    float* Pbuf     = (float*)w; w += (size_t)NCHUNK * DN * 4;            // 8 MB
    float* Sbuf     = (float*)w; w += (size_t)NCHUNK * DN * 4;            // 8 MB
    float* Hinit    = (float*)w; w += (size_t)NCHUNK * DN * 4;            // 8 MB
    float* xp_part  = (float*)w; w += (size_t)KSPL_X * LSEQ * 128 * 4;    // 16 MB
    float* out_part = (float*)reuse0;   // 32 MB

    prep_kernel<<<LSEQ + (NCAST4 + 255) / 256, 256, 0, stream>>>(
        x, norm_w, xn, W_in, W_out, W_xproj, W_dt, W_in_b, W_out_b, W_xproj_b, W_dt_b);

    // in_proj: (2048 x 4096) = xn (2048x1024) * W_in^T
    gemm_fast<0><<<dim3(4096 / 128, 2048 / 128, 1), 512, 0, stream>>>(
        xn, W_in_b, 2048, 4096, 1024, 1024, nullptr, xz, nullptr);

    conv_kernel<<<(LSEQ / 4) * (D_INNER / 2) / 256, 256, 0, stream>>>(xz, conv_w, conv_b, xsb);

    // x_proj: (2048 x 96) = xsb (2048x2048) * W_xproj^T, split-K=16, N padded to 128
    gemm_fast<4><<<dim3(1, 2048 / 128, KSPL_X), 512, 0, stream>>>(
        xsb, W_xproj_b, 2048, 128, 2048, 2048 / KSPL_X, xp_part, nullptr, nullptr);
    reduce_xproj<<<LSEQ, 128, 0, stream>>>(xp_part, dbc, dtb);

    // delta: (2048 x 2048) = dtb (2048x64) * W_dt^T, softplus+bias epilogue
    gemm_fast<2><<<dim3(2048 / 128, 2048 / 128, 1), 512, 0, stream>>>(
        dtb, W_dt_b, 2048, 2048, 64, 64, nullptr, delta, b_dt);

    // fused chunked scan (cooperative: 2 grid syncs inside)
    {
        void* args[] = {(void*)&delta, (void*)&xsb, (void*)&dbc, (void*)&xz,
                        (void*)&A_log, (void*)&Dw, (void*)&Pbuf, (void*)&Sbuf,
                        (void*)&Hinit, (void*)&yg};
        hipLaunchCooperativeKernel((void*)scan_fused, dim3(D_INNER / 256, NCHUNK),
                                   dim3(256), args, 0, stream);
    }

    // out_proj: (2048 x 1024) = yg (2048x2048) * W_out^T, split-K=4
    gemm_fast<4><<<dim3(1024 / 128, 2048 / 128, KSPL_O), 512, 0, stream>>>(
        yg, W_out_b, 2048, 1024, 2048, 2048 / KSPL_O, out_part, nullptr, nullptr);
    reduce_out<<<LSEQ * D_MODEL / 4 / 256, 256, 0, stream>>>(out_part, x, (float*)d_out);
}

// Round 9
// 248.437 us; speedup vs baseline: 1.6119x; 1.6119x over previous
//
#include <hip/hip_runtime.h>
#include <hip/hip_bf16.h>

#define D_MODEL 1024
#define D_INNER 2048
#define DT_RANK 64
#define D_STATE 16
#define LSEQ    2048
#define CHUNK   32
#define NCHUNK  (LSEQ / CHUNK)       // 64
#define DN      (D_INNER * D_STATE)  // 32768
#define KSPL_O  4                    // split-K for out-proj
#define KSPL_X  16                   // split-K for x-proj

typedef __attribute__((ext_vector_type(8))) short  short8;
typedef __attribute__((ext_vector_type(4))) float  float4v;
typedef __hip_bfloat16 bf16;

static __device__ __forceinline__ float b2f(bf16 v) { return __bfloat162float(v); }
static __device__ __forceinline__ bf16  f2b(float v) { return __float2bfloat16(v); }
static __device__ __forceinline__ float us2f(unsigned short u) {
    union { unsigned int i; float f; } cc; cc.i = ((unsigned int)u) << 16; return cc.f;
}
static __device__ __forceinline__ unsigned short f2us(float v) {
    return __bfloat16_as_ushort(__float2bfloat16(v));
}

#define GLOAD_LDS16(g, l)                                                          \
    __builtin_amdgcn_global_load_lds((const __attribute__((address_space(1))) void*)(g), \
                                     (__attribute__((address_space(3))) void*)(l), 16, 0, 0)

// ---------------------- fused prep: RMSNorm (blocks 0..2047) + weight casts ----
#define N1 (2 * D_INNER * D_MODEL)   // W_in
#define N2 (D_MODEL * D_INNER)       // W_out
#define N3 (96 * D_INNER)            // W_xproj
#define N4 (D_INNER * DT_RANK)       // W_dt
#define NCAST4 ((N1 + N2 + N3 + N4) / 4)
__global__ __launch_bounds__(256)
void prep_kernel(const float* __restrict__ x, const float* __restrict__ nw,
                 bf16* __restrict__ xn,
                 const float* __restrict__ w_in, const float* __restrict__ w_out,
                 const float* __restrict__ w_xp, const float* __restrict__ w_dt,
                 bf16* __restrict__ o_in, bf16* __restrict__ o_out,
                 bf16* __restrict__ o_xp, bf16* __restrict__ o_dt) {
    int t = threadIdx.x;
    if (blockIdx.x < LSEQ) {   // RMSNorm row
        int l = blockIdx.x;
        float4v v = ((const float4v*)(x + (size_t)l * D_MODEL))[t];
        float ssq = v[0]*v[0] + v[1]*v[1] + v[2]*v[2] + v[3]*v[3];
        for (int o = 32; o > 0; o >>= 1) ssq += __shfl_down(ssq, o);
        __shared__ float part[4];
        int lane = t & 63, wid = t >> 6;
        if (lane == 0) part[wid] = ssq;
        __syncthreads();
        float tot = part[0] + part[1] + part[2] + part[3];
        float sc = rsqrtf(tot * (1.0f / D_MODEL) + 1e-5f);
        float4v nv = ((const float4v*)nw)[t];
        bf16* op = xn + (size_t)l * D_MODEL + t * 4;
        op[0] = f2b(v[0] * sc * nv[0]);
        op[1] = f2b(v[1] * sc * nv[1]);
        op[2] = f2b(v[2] * sc * nv[2]);
        op[3] = f2b(v[3] * sc * nv[3]);
        return;
    }
    int i4 = (blockIdx.x - LSEQ) * 256 + t;
    if (i4 >= NCAST4) return;
    const float* src; bf16* dst; int base;
    if (i4 < N1 / 4)                { src = w_in;  dst = o_in;  base = 0; }
    else if (i4 < (N1 + N2) / 4)    { src = w_out; dst = o_out; base = N1 / 4; }
    else if (i4 < (N1+N2+N3) / 4)   { src = w_xp;  dst = o_xp;  base = (N1+N2) / 4; }
    else                            { src = w_dt;  dst = o_dt;  base = (N1+N2+N3) / 4; }
    int j = i4 - base;
    float4v v = ((const float4v*)src)[j];
    bf16* o = dst + j * 4;
    o[0] = f2b(v[0]); o[1] = f2b(v[1]); o[2] = f2b(v[2]); o[3] = f2b(v[3]);
}

// ---- fast NT GEMM: 512 threads / 8 waves, wave tile 32x64, BK=64, dbuf LDS ---
// C[M,N] = A[M,K]*B[N,K]^T. Tiles 128x128. kLen%64==0.
// LDS physical 16B-chunk = logical chunk ^ (row&7) -> conflict-free stage+read.
// XCD-aware block swizzle: cluster tiles sharing A/B slabs onto one XCD's L2.
// MODE 0: outB = bf16(acc)                       (xz)
// MODE 2: outB = bf16(softplus(acc+bias[n]))     (delta)
// MODE 4: outF[z-slice] = acc                    (split-K partials)
template <int MODE>
__global__ __launch_bounds__(512)
void gemm_fast(const bf16* __restrict__ Ab, const bf16* __restrict__ Bb,
               int M, int N, int K, int kLen,
               float* __restrict__ outF, bf16* __restrict__ outB,
               const float* __restrict__ bias) {
    __shared__ short As[2][128 * 64];   // 16 KB per buffer
    __shared__ short Bs[2][128 * 64];
    const short* Ap = (const short*)Ab;
    const short* Bp = (const short*)Bb;

    int t = threadIdx.x;
    int lane = t & 63, wid = t >> 6;            // 8 waves

    // ---- XCD swizzle (assignment heuristic: linear block id % 8 -> XCD) ----
    int bx, by, bz;
    if (MODE == 0) {            // grid 32x16x1: 8 windows of 8bx x 8by (~4MB/XCD)
        int id = blockIdx.y * gridDim.x + blockIdx.x;
        int xcd = id & 7, slot = id >> 3;       // slot 0..63
        bx = (xcd & 3) * 8 + (slot & 7);
        by = (xcd >> 2) * 8 + (slot >> 3);
        bz = 0;
    } else if (MODE == 4) {     // z-split grids: per-XCD (by,z) windows
        int id = (blockIdx.z * gridDim.y + blockIdx.y) * gridDim.x + blockIdx.x;
        int xcd = id & 7, slot = id >> 3;
        bx = slot % gridDim.x;
        int byz = xcd * ((gridDim.y * gridDim.z) / 8) + slot / gridDim.x;
        by = byz % gridDim.y;
        bz = byz / gridDim.y;
    } else {
        bx = blockIdx.x; by = blockIdx.y; bz = blockIdx.z;
    }
    int mBase = by * 128, nBase = bx * 128;
    int kBase = bz * kLen;
    int wm = 32 * (wid >> 1), wn = 64 * (wid & 1);   // wave tile 32x64
    int lr = lane & 15, quad = lane >> 4;

    // staging: wave wid owns rows [16*wid, 16*wid+16); 2 instrs of 8 rows each.
    int srow = 16 * wid + (lane >> 3);
    int cg2 = (lane & 7) ^ (lane >> 3);         // global chunk for phys chunk lane&7
    const short* gA = Ap + (size_t)(mBase + srow) * K + cg2 * 8;
    const short* gB = Bp + (size_t)(nBase + srow) * K + cg2 * 8;

    float4v acc[2][4] = {};

    // prologue: stage first K-slab into buf 0
    #pragma unroll
    for (int g = 0; g < 2; ++g) {
        GLOAD_LDS16(gA + (size_t)g * 8 * K + kBase, &As[0][(16 * wid + g * 8) * 64]);
        GLOAD_LDS16(gB + (size_t)g * 8 * K + kBase, &Bs[0][(16 * wid + g * 8) * 64]);
    }

    int p = 0;
    for (int kt = kBase; kt < kBase + kLen; kt += 64, p ^= 1) {
        __syncthreads();   // drains buf[p] loads; all waves past buf[p^1] reads
        if (kt + 64 < kBase + kLen) {
            int kn = kt + 64, q = p ^ 1;
            #pragma unroll
            for (int g = 0; g < 2; ++g) {
                GLOAD_LDS16(gA + (size_t)g * 8 * K + kn, &As[q][(16 * wid + g * 8) * 64]);
                GLOAD_LDS16(gB + (size_t)g * 8 * K + kn, &Bs[q][(16 * wid + g * 8) * 64]);
            }
        }
        #pragma unroll
        for (int s = 0; s < 2; ++s) {
            short8 af[2], bfr[4];
            #pragma unroll
            for (int i = 0; i < 2; ++i) {
                int row = wm + i * 16 + lr;
                af[i] = *(const short8*)&As[p][row * 64 + (((s * 4 + quad) ^ (lr & 7)) * 8)];
            }
            #pragma unroll
            for (int j = 0; j < 4; ++j) {
                int row = wn + j * 16 + lr;
                bfr[j] = *(const short8*)&Bs[p][row * 64 + (((s * 4 + quad) ^ (lr & 7)) * 8)];
            }
            #pragma unroll
            for (int i = 0; i < 2; ++i)
                #pragma unroll
                for (int j = 0; j < 4; ++j)
                    acc[i][j] = __builtin_amdgcn_mfma_f32_16x16x32_bf16(af[i], bfr[j], acc[i][j], 0, 0, 0);
        }
    }

    #pragma unroll
    for (int i = 0; i < 2; ++i) {
        #pragma unroll
        for (int j = 0; j < 4; ++j) {
            #pragma unroll
            for (int r = 0; r < 4; ++r) {
                int gm = mBase + wm + i * 16 + quad * 4 + r;
                int gn = nBase + wn + j * 16 + lr;
                float v = acc[i][j][r];
                if (MODE == 0) {
                    outB[(size_t)gm * N + gn] = f2b(v);
                } else if (MODE == 2) {
                    v += bias[gn];
                    v = (v > 20.0f) ? v : log1pf(__expf(v));
                    outB[(size_t)gm * N + gn] = f2b(v);
                } else {  // MODE 4: split-K partials
                    outF[((size_t)bz * M + gm) * N + gn] = v;
                }
            }
        }
    }
}

// --------------- x_proj reduce: dbc = sum_z part, + dt bf16 cast (fused) ------
__global__ __launch_bounds__(128)
void reduce_xproj(const float* __restrict__ part, float* __restrict__ dbc,
                  bf16* __restrict__ dtb) {
    int m = blockIdx.x, j = threadIdx.x;
    if (j >= 96) return;
    float v = 0.0f;
    #pragma unroll
    for (int z = 0; z < KSPL_X; ++z)
        v += part[((size_t)z * LSEQ + m) * 128 + j];
    dbc[(size_t)m * 96 + j] = v;
    if (j < DT_RANK) dtb[(size_t)m * DT_RANK + j] = f2b(v);
}

// --------------- out reduce: d_out = sum_z part + x (residual fused) ----------
__global__ __launch_bounds__(256)
void reduce_out(const float* __restrict__ part, const float* __restrict__ x,
                float* __restrict__ out) {
    int i = blockIdx.x * 256 + threadIdx.x;   // float4 over M*N/4
    const int MN4 = LSEQ * D_MODEL / 4;
    float4v a = ((const float4v*)part)[i];
    #pragma unroll
    for (int z = 1; z < KSPL_O; ++z) {
        float4v b = ((const float4v*)part)[(size_t)z * MN4 + i];
        a[0] += b[0]; a[1] += b[1]; a[2] += b[2]; a[3] += b[3];
    }
    float4v xv = ((const float4v*)x)[i];
    a[0] += xv[0]; a[1] += xv[1]; a[2] += xv[2]; a[3] += xv[3];
    ((float4v*)out)[i] = a;
}

// ------------- depthwise causal conv+SiLU, 2 channels x 4 timesteps/thread ----
__global__ void conv_kernel(const bf16* __restrict__ xz, const float* __restrict__ cw,
                            const float* __restrict__ cb, bf16* __restrict__ xsb) {
    int idx = blockIdx.x * 256 + threadIdx.x;   // over (LSEQ/4)*(D_INNER/2)
    int c = (idx & (D_INNER / 2 - 1)) * 2;
    int l0 = (idx >> 10) * 4;
    float4v wA = ((const float4v*)cw)[c];       // cw row c: 4 floats
    float4v wB = ((const float4v*)cw)[c + 1];
    float bA = cb[c], bB = cb[c + 1];
    const unsigned int* col = (const unsigned int*)((const unsigned short*)xz + c);
    float vA[7], vB[7];
    #pragma unroll
    for (int j = 0; j < 7; ++j) {
        int l = l0 - 3 + j;
        if (l >= 0) {
            unsigned int u = col[(size_t)l * D_INNER];   // 2 bf16 = 4B, stride 2*D_INNER shorts
            vA[j] = us2f((unsigned short)(u & 0xffff));
            vB[j] = us2f((unsigned short)(u >> 16));
        } else { vA[j] = 0.0f; vB[j] = 0.0f; }
    }
    #pragma unroll
    for (int j = 0; j < 4; ++j) {
        float aA = bA + vA[j]*wA[0] + vA[j+1]*wA[1] + vA[j+2]*wA[2] + vA[j+3]*wA[3];
        float aB = bB + vB[j]*wB[0] + vB[j+1]*wB[1] + vB[j+2]*wB[2] + vB[j+3]*wB[3];
        float sA = aA * (1.0f / (1.0f + __expf(-aA)));
        float sB = aB * (1.0f / (1.0f + __expf(-aB)));
        unsigned int o = (unsigned int)f2us(sA) | ((unsigned int)f2us(sB) << 16);
        *(unsigned int*)((unsigned short*)xsb + (size_t)(l0 + j) * D_INNER + c) = o;
    }
}

// ------------------------------- chunked selective scan, states in registers --
template <int PASS>
__global__ __launch_bounds__(256)
void scan2(const bf16* __restrict__ delta, const bf16* __restrict__ xsb,
           const float* __restrict__ dbc, const bf16* __restrict__ xz,
           const float* __restrict__ A_log, const float* __restrict__ Dw,
           const float* __restrict__ Hinit,
           float* __restrict__ P, float* __restrict__ S, bf16* __restrict__ yg) {
    __shared__ float bc[CHUNK][32];   // [l][B(16)|C(16)]
    int t = threadIdx.x;
    int d = blockIdx.x * 256 + t;
    int c = blockIdx.y;
    int l0 = c * CHUNK;

    {   // stage B,C for this chunk: 32 rows x 32 floats = 4 KB
        int row = t >> 3, col = (t & 7) * 4;
        *(float4v*)&bc[row][col] = *(const float4v*)&dbc[(size_t)(l0 + row) * 96 + 64 + col];
    }
    __syncthreads();

    float A[16], h[16], pr[16];
    #pragma unroll
    for (int n = 0; n < 16; ++n) A[n] = -__expf(A_log[(size_t)d * 16 + n]);
    if (PASS == 0) {
        #pragma unroll
        for (int n = 0; n < 16; ++n) { h[n] = 0.0f; pr[n] = 1.0f; }
    } else {
        #pragma unroll
        for (int n = 0; n < 16; n += 4)
            *(float4v*)&h[n] = *(const float4v*)&Hinit[(size_t)c * DN + (size_t)d * 16 + n];
    }
    float Dd = (PASS == 1) ? Dw[d] : 0.0f;

    for (int i = 0; i < CHUNK; ++i) {
        int l = l0 + i;
        float dv = b2f(delta[(size_t)l * D_INNER + d]);
        float xv = b2f(xsb[(size_t)l * D_INNER + d]);
        float u = dv * xv;
        #pragma unroll
        for (int n = 0; n < 16; ++n) {
            float a = __expf(dv * A[n]);
            h[n] = fmaf(a, h[n], bc[i][n] * u);
            if (PASS == 0) pr[n] *= a;
        }
        if (PASS == 1) {
            float y = xv * Dd;
            #pragma unroll
            for (int n = 0; n < 16; ++n) y = fmaf(h[n], bc[i][16 + n], y);
            float r = b2f(xz[(size_t)l * (2 * D_INNER) + D_INNER + d]);
            float g = r * (1.0f / (1.0f + __expf(-r)));
            yg[(size_t)l * D_INNER + d] = f2b(y * g);
        }
    }
    if (PASS == 0) {
        #pragma unroll
        for (int n = 0; n < 16; n += 4) {
            *(float4v*)&P[(size_t)c * DN + (size_t)d * 16 + n] = *(float4v*)&pr[n];
            *(float4v*)&S[(size_t)c * DN + (size_t)d * 16 + n] = *(float4v*)&h[n];
        }
    }
}

// Sequential compose over chunks: h_init[c+1] = P[c]*h_init[c] + S[c].
__global__ __launch_bounds__(256)
void scan_mid(const float* __restrict__ P, const float* __restrict__ S,
              float* __restrict__ Hinit) {
    int idx = blockIdx.x * 256 + threadIdx.x;   // over DN
    float h = 0.0f;
    for (int c0 = 0; c0 < NCHUNK; c0 += 8) {
        float p[8], s[8];
        #pragma unroll
        for (int j = 0; j < 8; ++j) {
            p[j] = P[(size_t)(c0 + j) * DN + idx];
            s[j] = S[(size_t)(c0 + j) * DN + idx];
        }
        #pragma unroll
        for (int j = 0; j < 8; ++j) {
            Hinit[(size_t)(c0 + j) * DN + idx] = h;
            h = fmaf(p[j], h, s[j]);
        }
    }
}

// -------------------------------------------------------------- launcher ----
extern "C" void kernel_launch(void* const* d_in, const int* in_sizes, int n_in,
                              void* d_out, int out_size, void* d_ws, size_t ws_size,
                              hipStream_t stream) {
    const float* x       = (const float*)d_in[0];
    const float* W_in    = (const float*)d_in[1];
    const float* conv_w  = (const float*)d_in[2];
    const float* conv_b  = (const float*)d_in[3];
    const float* W_xproj = (const float*)d_in[4];
    const float* W_dt    = (const float*)d_in[5];
    const float* b_dt    = (const float*)d_in[6];
    const float* A_log   = (const float*)d_in[7];
    const float* Dw      = (const float*)d_in[8];
    const float* W_out   = (const float*)d_in[9];
    const float* norm_w  = (const float*)d_in[10];

    char* w = (char*)d_ws;
    bf16* W_in_b    = (bf16*)w; w += (size_t)2 * D_INNER * D_MODEL * 2;   // 8 MB
    bf16* W_out_b   = (bf16*)w; w += (size_t)D_MODEL * D_INNER * 2;       // 4 MB
    bf16* W_xproj_b = (bf16*)w; w += (size_t)128 * D_INNER * 2;           // 512 KB (rows 96..127 pad)
    bf16* W_dt_b    = (bf16*)w; w += (size_t)D_INNER * DT_RANK * 2;       // 256 KB
    char* reuse0 = w;   // aliased by out_part after scan
    bf16* xn        = (bf16*)w; w += (size_t)LSEQ * D_MODEL * 2;          // 4 MB
    bf16* xz        = (bf16*)w; w += (size_t)LSEQ * 2 * D_INNER * 2;      // 16 MB
    bf16* xsb       = (bf16*)w; w += (size_t)LSEQ * D_INNER * 2;          // 8 MB
    bf16* delta     = (bf16*)w; w += (size_t)LSEQ * D_INNER * 2;          // 8 MB  (36 MB pool)
    float* dbc      = (float*)w; w += (size_t)LSEQ * 96 * 4;              // 768 KB
    bf16* dtb       = (bf16*)w; w += (size_t)LSEQ * DT_RANK * 2;          // 256 KB
    bf16* yg        = (bf16*)w; w += (size_t)LSEQ * D_INNER * 2;          // 8 MB
    float* Pbuf     = (float*)w; w += (size_t)NCHUNK * DN * 4;            // 8 MB
    float* Sbuf     = (float*)w; w += (size_t)NCHUNK * DN * 4;            // 8 MB
    float* Hinit    = (float*)w; w += (size_t)NCHUNK * DN * 4;            // 8 MB
    float* xp_part  = (float*)w; w += (size_t)KSPL_X * LSEQ * 128 * 4;    // 16 MB
    float* out_part = (float*)reuse0;   // 32 MB

    prep_kernel<<<LSEQ + (NCAST4 + 255) / 256, 256, 0, stream>>>(
        x, norm_w, xn, W_in, W_out, W_xproj, W_dt, W_in_b, W_out_b, W_xproj_b, W_dt_b);

    // in_proj: (2048 x 4096) = xn (2048x1024) * W_in^T
    gemm_fast<0><<<dim3(4096 / 128, 2048 / 128, 1), 512, 0, stream>>>(
        xn, W_in_b, 2048, 4096, 1024, 1024, nullptr, xz, nullptr);

    conv_kernel<<<(LSEQ / 4) * (D_INNER / 2) / 256, 256, 0, stream>>>(xz, conv_w, conv_b, xsb);

    // x_proj: (2048 x 96) = xsb (2048x2048) * W_xproj^T, split-K=16, N padded to 128
    gemm_fast<4><<<dim3(1, 2048 / 128, KSPL_X), 512, 0, stream>>>(
        xsb, W_xproj_b, 2048, 128, 2048, 2048 / KSPL_X, xp_part, nullptr, nullptr);
    reduce_xproj<<<LSEQ, 128, 0, stream>>>(xp_part, dbc, dtb);

    // delta: (2048 x 2048) = dtb (2048x64) * W_dt^T, softplus+bias epilogue
    gemm_fast<2><<<dim3(2048 / 128, 2048 / 128, 1), 512, 0, stream>>>(
        dtb, W_dt_b, 2048, 2048, 64, 64, nullptr, delta, b_dt);

    dim3 sgrid(D_INNER / 256, NCHUNK);
    scan2<0><<<sgrid, 256, 0, stream>>>(delta, xsb, dbc, xz, A_log, Dw,
                                        nullptr, Pbuf, Sbuf, nullptr);
    scan_mid<<<DN / 256, 256, 0, stream>>>(Pbuf, Sbuf, Hinit);
    scan2<1><<<sgrid, 256, 0, stream>>>(delta, xsb, dbc, xz, A_log, Dw,
                                        Hinit, nullptr, nullptr, yg);

    // out_proj: (2048 x 1024) = yg (2048x2048) * W_out^T, split-K=4
    gemm_fast<4><<<dim3(1024 / 128, 2048 / 128, KSPL_O), 512, 0, stream>>>(
        yg, W_out_b, 2048, 1024, 2048, 2048 / KSPL_O, out_part, nullptr, nullptr);
    reduce_out<<<LSEQ * D_MODEL / 4 / 256, 256, 0, stream>>>(out_part, x, (float*)d_out);
}

// Round 10
// 240.958 us; speedup vs baseline: 1.6619x; 1.0310x over previous
//
#include <hip/hip_runtime.h>
#include <hip/hip_bf16.h>

#define D_MODEL 1024
#define D_INNER 2048
#define DT_RANK 64
#define D_STATE 16
#define LSEQ    2048
#define CHUNK   32
#define NCHUNK  (LSEQ / CHUNK)       // 64
#define DN      (D_INNER * D_STATE)  // 32768
#define KSPL_O  4                    // split-K for out-proj
#define KSPL_X  16                   // split-K for x-proj

typedef __attribute__((ext_vector_type(8))) short  short8;
typedef __attribute__((ext_vector_type(4))) short  short4v;
typedef __attribute__((ext_vector_type(4))) float  float4v;
typedef __hip_bfloat16 bf16;

static __device__ __forceinline__ float b2f(bf16 v) { return __bfloat162float(v); }
static __device__ __forceinline__ bf16  f2b(float v) { return __float2bfloat16(v); }
static __device__ __forceinline__ float us2f(unsigned short u) {
    union { unsigned int i; float f; } cc; cc.i = ((unsigned int)u) << 16; return cc.f;
}
static __device__ __forceinline__ unsigned short f2us(float v) {
    return __bfloat16_as_ushort(__float2bfloat16(v));
}

#define GLOAD_LDS16(g, l)                                                          \
    __builtin_amdgcn_global_load_lds((const __attribute__((address_space(1))) void*)(g), \
                                     (__attribute__((address_space(3))) void*)(l), 16, 0, 0)

// ---------------------- fused prep: RMSNorm (blocks 0..2047) + weight casts ----
#define N1 (2 * D_INNER * D_MODEL)   // W_in
#define N2 (D_MODEL * D_INNER)       // W_out
#define N3 (96 * D_INNER)            // W_xproj
#define N4 (D_INNER * DT_RANK)       // W_dt
#define NCAST4 ((N1 + N2 + N3 + N4) / 4)
__global__ __launch_bounds__(256)
void prep_kernel(const float* __restrict__ x, const float* __restrict__ nw,
                 bf16* __restrict__ xn,
                 const float* __restrict__ w_in, const float* __restrict__ w_out,
                 const float* __restrict__ w_xp, const float* __restrict__ w_dt,
                 bf16* __restrict__ o_in, bf16* __restrict__ o_out,
                 bf16* __restrict__ o_xp, bf16* __restrict__ o_dt) {
    int t = threadIdx.x;
    if (blockIdx.x < LSEQ) {   // RMSNorm row
        int l = blockIdx.x;
        float4v v = ((const float4v*)(x + (size_t)l * D_MODEL))[t];
        float ssq = v[0]*v[0] + v[1]*v[1] + v[2]*v[2] + v[3]*v[3];
        for (int o = 32; o > 0; o >>= 1) ssq += __shfl_down(ssq, o);
        __shared__ float part[4];
        int lane = t & 63, wid = t >> 6;
        if (lane == 0) part[wid] = ssq;
        __syncthreads();
        float tot = part[0] + part[1] + part[2] + part[3];
        float sc = rsqrtf(tot * (1.0f / D_MODEL) + 1e-5f);
        float4v nv = ((const float4v*)nw)[t];
        bf16* op = xn + (size_t)l * D_MODEL + t * 4;
        op[0] = f2b(v[0] * sc * nv[0]);
        op[1] = f2b(v[1] * sc * nv[1]);
        op[2] = f2b(v[2] * sc * nv[2]);
        op[3] = f2b(v[3] * sc * nv[3]);
        return;
    }
    int i4 = (blockIdx.x - LSEQ) * 256 + t;
    if (i4 >= NCAST4) return;
    const float* src; bf16* dst; int base;
    if (i4 < N1 / 4)                { src = w_in;  dst = o_in;  base = 0; }
    else if (i4 < (N1 + N2) / 4)    { src = w_out; dst = o_out; base = N1 / 4; }
    else if (i4 < (N1+N2+N3) / 4)   { src = w_xp;  dst = o_xp;  base = (N1+N2) / 4; }
    else                            { src = w_dt;  dst = o_dt;  base = (N1+N2+N3) / 4; }
    int j = i4 - base;
    float4v v = ((const float4v*)src)[j];
    bf16* o = dst + j * 4;
    o[0] = f2b(v[0]); o[1] = f2b(v[1]); o[2] = f2b(v[2]); o[3] = f2b(v[3]);
}

// ---- fast NT GEMM: 512 threads / 8 waves, wave tile 32x64, BK=64, dbuf LDS ---
// C[M,N] = A[M,K]*B[N,K]^T. Tiles 128x128. kLen%64==0.
// LDS physical 16B-chunk = logical chunk ^ (row&7) -> conflict-free stage+read.
// MODE 0: outB = bf16(acc)                       (xz)
// MODE 2: outB = bf16(softplus(acc+bias[n]))     (delta)
// MODE 4: outF[z-slice] = acc       fp32 partials (x-proj)
// MODE 5: outB[z-slice] = bf16(acc) bf16 partials (out-proj)
template <int MODE>
__global__ __launch_bounds__(512)
void gemm_fast(const bf16* __restrict__ Ab, const bf16* __restrict__ Bb,
               int M, int N, int K, int kLen,
               float* __restrict__ outF, bf16* __restrict__ outB,
               const float* __restrict__ bias) {
    __shared__ short As[2][128 * 64];   // 16 KB per buffer
    __shared__ short Bs[2][128 * 64];
    const short* Ap = (const short*)Ab;
    const short* Bp = (const short*)Bb;

    int t = threadIdx.x;
    int lane = t & 63, wid = t >> 6;            // 8 waves
    int mBase = blockIdx.y * 128, nBase = blockIdx.x * 128;
    int kBase = blockIdx.z * kLen;
    int wm = 32 * (wid >> 1), wn = 64 * (wid & 1);   // wave tile 32x64
    int lr = lane & 15, quad = lane >> 4;

    // staging: wave wid owns rows [16*wid, 16*wid+16); 2 instrs of 8 rows each.
    int srow = 16 * wid + (lane >> 3);
    int cg2 = (lane & 7) ^ (lane >> 3);         // global chunk for phys chunk lane&7
    const short* gA = Ap + (size_t)(mBase + srow) * K + cg2 * 8;
    const short* gB = Bp + (size_t)(nBase + srow) * K + cg2 * 8;

    float4v acc[2][4] = {};

    // prologue: stage first K-slab into buf 0
    #pragma unroll
    for (int g = 0; g < 2; ++g) {
        GLOAD_LDS16(gA + (size_t)g * 8 * K + kBase, &As[0][(16 * wid + g * 8) * 64]);
        GLOAD_LDS16(gB + (size_t)g * 8 * K + kBase, &Bs[0][(16 * wid + g * 8) * 64]);
    }

    int p = 0;
    for (int kt = kBase; kt < kBase + kLen; kt += 64, p ^= 1) {
        __syncthreads();   // drains buf[p] loads; all waves past buf[p^1] reads
        if (kt + 64 < kBase + kLen) {
            int kn = kt + 64, q = p ^ 1;
            #pragma unroll
            for (int g = 0; g < 2; ++g) {
                GLOAD_LDS16(gA + (size_t)g * 8 * K + kn, &As[q][(16 * wid + g * 8) * 64]);
                GLOAD_LDS16(gB + (size_t)g * 8 * K + kn, &Bs[q][(16 * wid + g * 8) * 64]);
            }
        }
        #pragma unroll
        for (int s = 0; s < 2; ++s) {
            short8 af[2], bfr[4];
            #pragma unroll
            for (int i = 0; i < 2; ++i) {
                int row = wm + i * 16 + lr;
                af[i] = *(const short8*)&As[p][row * 64 + (((s * 4 + quad) ^ (lr & 7)) * 8)];
            }
            #pragma unroll
            for (int j = 0; j < 4; ++j) {
                int row = wn + j * 16 + lr;
                bfr[j] = *(const short8*)&Bs[p][row * 64 + (((s * 4 + quad) ^ (lr & 7)) * 8)];
            }
            #pragma unroll
            for (int i = 0; i < 2; ++i)
                #pragma unroll
                for (int j = 0; j < 4; ++j)
                    acc[i][j] = __builtin_amdgcn_mfma_f32_16x16x32_bf16(af[i], bfr[j], acc[i][j], 0, 0, 0);
        }
    }

    #pragma unroll
    for (int i = 0; i < 2; ++i) {
        #pragma unroll
        for (int j = 0; j < 4; ++j) {
            #pragma unroll
            for (int r = 0; r < 4; ++r) {
                int gm = mBase + wm + i * 16 + quad * 4 + r;
                int gn = nBase + wn + j * 16 + lr;
                float v = acc[i][j][r];
                if (MODE == 0) {
                    outB[(size_t)gm * N + gn] = f2b(v);
                } else if (MODE == 2) {
                    v += bias[gn];
                    v = (v > 20.0f) ? v : log1pf(__expf(v));
                    outB[(size_t)gm * N + gn] = f2b(v);
                } else if (MODE == 4) {
                    outF[((size_t)blockIdx.z * M + gm) * N + gn] = v;
                } else {  // MODE 5: bf16 split-K partials
                    outB[((size_t)blockIdx.z * M + gm) * N + gn] = f2b(v);
                }
            }
        }
    }
}

// --------------- x_proj reduce: dbc = sum_z part, + dt bf16 cast (fused) ------
__global__ __launch_bounds__(128)
void reduce_xproj(const float* __restrict__ part, float* __restrict__ dbc,
                  bf16* __restrict__ dtb) {
    int m = blockIdx.x, j = threadIdx.x;
    if (j >= 96) return;
    float v = 0.0f;
    #pragma unroll
    for (int z = 0; z < KSPL_X; ++z)
        v += part[((size_t)z * LSEQ + m) * 128 + j];
    dbc[(size_t)m * 96 + j] = v;
    if (j < DT_RANK) dtb[(size_t)m * DT_RANK + j] = f2b(v);
}

// --------- out reduce: d_out = sum_z bf16 part + x (residual fused) -----------
__global__ __launch_bounds__(256)
void reduce_out(const bf16* __restrict__ part, const float* __restrict__ x,
                float* __restrict__ out) {
    int i = blockIdx.x * 256 + threadIdx.x;   // float4 over M*N/4
    const size_t MN = (size_t)LSEQ * D_MODEL;
    float a0 = 0, a1 = 0, a2 = 0, a3 = 0;
    #pragma unroll
    for (int z = 0; z < KSPL_O; ++z) {
        short4v b = *(const short4v*)((const short*)part + z * MN + (size_t)i * 4);
        a0 += us2f((unsigned short)b[0]);
        a1 += us2f((unsigned short)b[1]);
        a2 += us2f((unsigned short)b[2]);
        a3 += us2f((unsigned short)b[3]);
    }
    float4v xv = ((const float4v*)x)[i];
    float4v o = {a0 + xv[0], a1 + xv[1], a2 + xv[2], a3 + xv[3]};
    ((float4v*)out)[i] = o;
}

// ------------- depthwise causal conv+SiLU, 2 channels x 4 timesteps/thread ----
__global__ void conv_kernel(const bf16* __restrict__ xz, const float* __restrict__ cw,
                            const float* __restrict__ cb, bf16* __restrict__ xsb) {
    int idx = blockIdx.x * 256 + threadIdx.x;   // over (LSEQ/4)*(D_INNER/2)
    int c = (idx & (D_INNER / 2 - 1)) * 2;
    int l0 = (idx >> 10) * 4;
    float4v wA = ((const float4v*)cw)[c];       // cw row c: 4 floats
    float4v wB = ((const float4v*)cw)[c + 1];
    float bA = cb[c], bB = cb[c + 1];
    const unsigned int* col = (const unsigned int*)((const unsigned short*)xz + c);
    float vA[7], vB[7];
    #pragma unroll
    for (int j = 0; j < 7; ++j) {
        int l = l0 - 3 + j;
        if (l >= 0) {
            unsigned int u = col[(size_t)l * D_INNER];   // 2 bf16 = 4B, stride 2*D_INNER shorts
            vA[j] = us2f((unsigned short)(u & 0xffff));
            vB[j] = us2f((unsigned short)(u >> 16));
        } else { vA[j] = 0.0f; vB[j] = 0.0f; }
    }
    #pragma unroll
    for (int j = 0; j < 4; ++j) {
        float aA = bA + vA[j]*wA[0] + vA[j+1]*wA[1] + vA[j+2]*wA[2] + vA[j+3]*wA[3];
        float aB = bB + vB[j]*wB[0] + vB[j+1]*wB[1] + vB[j+2]*wB[2] + vB[j+3]*wB[3];
        float sA = aA * (1.0f / (1.0f + __expf(-aA)));
        float sB = aB * (1.0f / (1.0f + __expf(-aB)));
        unsigned int o = (unsigned int)f2us(sA) | ((unsigned int)f2us(sB) << 16);
        *(unsigned int*)((unsigned short*)xsb + (size_t)(l0 + j) * D_INNER + c) = o;
    }
}

// ------------------------------- chunked selective scan, states in registers --
template <int PASS>
__global__ __launch_bounds__(256)
void scan2(const bf16* __restrict__ delta, const bf16* __restrict__ xsb,
           const float* __restrict__ dbc, const bf16* __restrict__ xz,
           const float* __restrict__ A_log, const float* __restrict__ Dw,
           const float* __restrict__ Hinit,
           float* __restrict__ P, float* __restrict__ S, bf16* __restrict__ yg) {
    __shared__ float bc[CHUNK][32];   // [l][B(16)|C(16)]
    int t = threadIdx.x;
    int d = blockIdx.x * 256 + t;
    int c = blockIdx.y;
    int l0 = c * CHUNK;

    {   // stage B,C for this chunk: 32 rows x 32 floats = 4 KB
        int row = t >> 3, col = (t & 7) * 4;
        *(float4v*)&bc[row][col] = *(const float4v*)&dbc[(size_t)(l0 + row) * 96 + 64 + col];
    }
    __syncthreads();

    float A[16], h[16], pr[16];
    #pragma unroll
    for (int n = 0; n < 16; ++n) A[n] = -__expf(A_log[(size_t)d * 16 + n]);
    if (PASS == 0) {
        #pragma unroll
        for (int n = 0; n < 16; ++n) { h[n] = 0.0f; pr[n] = 1.0f; }
    } else {
        #pragma unroll
        for (int n = 0; n < 16; n += 4)
            *(float4v*)&h[n] = *(const float4v*)&Hinit[(size_t)c * DN + (size_t)d * 16 + n];
    }
    float Dd = (PASS == 1) ? Dw[d] : 0.0f;

    for (int i = 0; i < CHUNK; ++i) {
        int l = l0 + i;
        float dv = b2f(delta[(size_t)l * D_INNER + d]);
        float xv = b2f(xsb[(size_t)l * D_INNER + d]);
        float u = dv * xv;
        #pragma unroll
        for (int n = 0; n < 16; ++n) {
            float a = __expf(dv * A[n]);
            h[n] = fmaf(a, h[n], bc[i][n] * u);
            if (PASS == 0) pr[n] *= a;
        }
        if (PASS == 1) {
            float y = xv * Dd;
            #pragma unroll
            for (int n = 0; n < 16; ++n) y = fmaf(h[n], bc[i][16 + n], y);
            float r = b2f(xz[(size_t)l * (2 * D_INNER) + D_INNER + d]);
            float g = r * (1.0f / (1.0f + __expf(-r)));
            yg[(size_t)l * D_INNER + d] = f2b(y * g);
        }
    }
    if (PASS == 0) {
        #pragma unroll
        for (int n = 0; n < 16; n += 4) {
            *(float4v*)&P[(size_t)c * DN + (size_t)d * 16 + n] = *(float4v*)&pr[n];
            *(float4v*)&S[(size_t)c * DN + (size_t)d * 16 + n] = *(float4v*)&h[n];
        }
    }
}

// Sequential compose over chunks: h_init[c+1] = P[c]*h_init[c] + S[c].
__global__ __launch_bounds__(256)
void scan_mid(const float* __restrict__ P, const float* __restrict__ S,
              float* __restrict__ Hinit) {
    int idx = blockIdx.x * 256 + threadIdx.x;   // over DN
    float h = 0.0f;
    for (int c0 = 0; c0 < NCHUNK; c0 += 8) {
        float p[8], s[8];
        #pragma unroll
        for (int j = 0; j < 8; ++j) {
            p[j] = P[(size_t)(c0 + j) * DN + idx];
            s[j] = S[(size_t)(c0 + j) * DN + idx];
        }
        #pragma unroll
        for (int j = 0; j < 8; ++j) {
            Hinit[(size_t)(c0 + j) * DN + idx] = h;
            h = fmaf(p[j], h, s[j]);
        }
    }
}

// -------------------------------------------------------------- launcher ----
extern "C" void kernel_launch(void* const* d_in, const int* in_sizes, int n_in,
                              void* d_out, int out_size, void* d_ws, size_t ws_size,
                              hipStream_t stream) {
    const float* x       = (const float*)d_in[0];
    const float* W_in    = (const float*)d_in[1];
    const float* conv_w  = (const float*)d_in[2];
    const float* conv_b  = (const float*)d_in[3];
    const float* W_xproj = (const float*)d_in[4];
    const float* W_dt    = (const float*)d_in[5];
    const float* b_dt    = (const float*)d_in[6];
    const float* A_log   = (const float*)d_in[7];
    const float* Dw      = (const float*)d_in[8];
    const float* W_out   = (const float*)d_in[9];
    const float* norm_w  = (const float*)d_in[10];

    char* w = (char*)d_ws;
    bf16* W_in_b    = (bf16*)w; w += (size_t)2 * D_INNER * D_MODEL * 2;   // 8 MB
    bf16* W_out_b   = (bf16*)w; w += (size_t)D_MODEL * D_INNER * 2;       // 4 MB
    bf16* W_xproj_b = (bf16*)w; w += (size_t)128 * D_INNER * 2;           // 512 KB (rows 96..127 pad)
    bf16* W_dt_b    = (bf16*)w; w += (size_t)D_INNER * DT_RANK * 2;       // 256 KB
    char* reuse0 = w;   // aliased by out_part after scan
    bf16* xn        = (bf16*)w; w += (size_t)LSEQ * D_MODEL * 2;          // 4 MB
    bf16* xz        = (bf16*)w; w += (size_t)LSEQ * 2 * D_INNER * 2;      // 16 MB
    bf16* xsb       = (bf16*)w; w += (size_t)LSEQ * D_INNER * 2;          // 8 MB
    bf16* delta     = (bf16*)w; w += (size_t)LSEQ * D_INNER * 2;          // 8 MB  (36 MB pool)
    float* dbc      = (float*)w; w += (size_t)LSEQ * 96 * 4;              // 768 KB
    bf16* dtb       = (bf16*)w; w += (size_t)LSEQ * DT_RANK * 2;          // 256 KB
    bf16* yg        = (bf16*)w; w += (size_t)LSEQ * D_INNER * 2;          // 8 MB
    float* Pbuf     = (float*)w; w += (size_t)NCHUNK * DN * 4;            // 8 MB
    float* Sbuf     = (float*)w; w += (size_t)NCHUNK * DN * 4;            // 8 MB
    float* Hinit    = (float*)w; w += (size_t)NCHUNK * DN * 4;            // 8 MB
    float* xp_part  = (float*)w; w += (size_t)KSPL_X * LSEQ * 128 * 4;    // 16 MB
    bf16* out_part  = (bf16*)reuse0;   // 16 MB bf16, aliases xn/xz (dead by then)

    prep_kernel<<<LSEQ + (NCAST4 + 255) / 256, 256, 0, stream>>>(
        x, norm_w, xn, W_in, W_out, W_xproj, W_dt, W_in_b, W_out_b, W_xproj_b, W_dt_b);

    // in_proj: (2048 x 4096) = xn (2048x1024) * W_in^T
    gemm_fast<0><<<dim3(4096 / 128, 2048 / 128, 1), 512, 0, stream>>>(
        xn, W_in_b, 2048, 4096, 1024, 1024, nullptr, xz, nullptr);

    conv_kernel<<<(LSEQ / 4) * (D_INNER / 2) / 256, 256, 0, stream>>>(xz, conv_w, conv_b, xsb);

    // x_proj: (2048 x 96) = xsb (2048x2048) * W_xproj^T, split-K=16, N padded to 128
    gemm_fast<4><<<dim3(1, 2048 / 128, KSPL_X), 512, 0, stream>>>(
        xsb, W_xproj_b, 2048, 128, 2048, 2048 / KSPL_X, xp_part, nullptr, nullptr);
    reduce_xproj<<<LSEQ, 128, 0, stream>>>(xp_part, dbc, dtb);

    // delta: (2048 x 2048) = dtb (2048x64) * W_dt^T, softplus+bias epilogue
    gemm_fast<2><<<dim3(2048 / 128, 2048 / 128, 1), 512, 0, stream>>>(
        dtb, W_dt_b, 2048, 2048, 64, 64, nullptr, delta, b_dt);

    dim3 sgrid(D_INNER / 256, NCHUNK);
    scan2<0><<<sgrid, 256, 0, stream>>>(delta, xsb, dbc, xz, A_log, Dw,
                                        nullptr, Pbuf, Sbuf, nullptr);
    scan_mid<<<DN / 256, 256, 0, stream>>>(Pbuf, Sbuf, Hinit);
    scan2<1><<<sgrid, 256, 0, stream>>>(delta, xsb, dbc, xz, A_log, Dw,
                                        Hinit, nullptr, nullptr, yg);

    // out_proj: (2048 x 1024) = yg (2048x2048) * W_out^T, split-K=4, bf16 partials
    gemm_fast<5><<<dim3(1024 / 128, 2048 / 128, KSPL_O), 512, 0, stream>>>(
        yg, W_out_b, 2048, 1024, 2048, 2048 / KSPL_O, nullptr, out_part, nullptr);
    reduce_out<<<LSEQ * D_MODEL / 4 / 256, 256, 0, stream>>>(out_part, x, (float*)d_out);
}

// Round 11
// 230.718 us; speedup vs baseline: 1.7357x; 1.0444x over previous
//
#include <hip/hip_runtime.h>
#include <hip/hip_bf16.h>

#define D_MODEL 1024
#define D_INNER 2048
#define DT_RANK 64
#define D_STATE 16
#define LSEQ    2048
#define CHUNK   32
#define NCHUNK  (LSEQ / CHUNK)       // 64
#define DN      (D_INNER * D_STATE)  // 32768
#define KSPL_O  4                    // split-K for out-proj
#define KSPL_X  16                   // split-K for x-proj

typedef __attribute__((ext_vector_type(8))) short  short8;
typedef __attribute__((ext_vector_type(4))) short  short4v;
typedef __attribute__((ext_vector_type(4))) float  float4v;
typedef __attribute__((ext_vector_type(4))) unsigned int uint4v;
typedef __hip_bfloat16 bf16;

static __device__ __forceinline__ float b2f(bf16 v) { return __bfloat162float(v); }
static __device__ __forceinline__ bf16  f2b(float v) { return __float2bfloat16(v); }
static __device__ __forceinline__ float us2f(unsigned short u) {
    union { unsigned int i; float f; } cc; cc.i = ((unsigned int)u) << 16; return cc.f;
}
static __device__ __forceinline__ unsigned short f2us(float v) {
    return __bfloat16_as_ushort(__float2bfloat16(v));
}

#define GLOAD_LDS16(g, l)                                                          \
    __builtin_amdgcn_global_load_lds((const __attribute__((address_space(1))) void*)(g), \
                                     (__attribute__((address_space(3))) void*)(l), 16, 0, 0)

// pack/unpack 16 floats <-> 16 bf16 (32 B) at 4B-aligned addresses
static __device__ __forceinline__ void st_bf16x16(bf16* dst, const float* v) {
    uint4v a, b;
    #pragma unroll
    for (int k = 0; k < 4; ++k)
        a[k] = (unsigned)f2us(v[2*k]) | ((unsigned)f2us(v[2*k+1]) << 16);
    #pragma unroll
    for (int k = 0; k < 4; ++k)
        b[k] = (unsigned)f2us(v[8+2*k]) | ((unsigned)f2us(v[8+2*k+1]) << 16);
    ((uint4v*)dst)[0] = a;
    ((uint4v*)dst)[1] = b;
}
static __device__ __forceinline__ void ld_bf16x16(const bf16* src, float* v) {
    uint4v a = ((const uint4v*)src)[0];
    uint4v b = ((const uint4v*)src)[1];
    #pragma unroll
    for (int k = 0; k < 4; ++k) {
        v[2*k]     = us2f((unsigned short)(a[k] & 0xffff));
        v[2*k+1]   = us2f((unsigned short)(a[k] >> 16));
        v[8+2*k]   = us2f((unsigned short)(b[k] & 0xffff));
        v[8+2*k+1] = us2f((unsigned short)(b[k] >> 16));
    }
}

// ---------------------- fused prep: RMSNorm (blocks 0..2047) + weight casts ----
#define N1 (2 * D_INNER * D_MODEL)   // W_in
#define N2 (D_MODEL * D_INNER)       // W_out
#define N3 (96 * D_INNER)            // W_xproj
#define N4 (D_INNER * DT_RANK)       // W_dt
#define NCAST4 ((N1 + N2 + N3 + N4) / 4)
__global__ __launch_bounds__(256)
void prep_kernel(const float* __restrict__ x, const float* __restrict__ nw,
                 bf16* __restrict__ xn,
                 const float* __restrict__ w_in, const float* __restrict__ w_out,
                 const float* __restrict__ w_xp, const float* __restrict__ w_dt,
                 bf16* __restrict__ o_in, bf16* __restrict__ o_out,
                 bf16* __restrict__ o_xp, bf16* __restrict__ o_dt) {
    int t = threadIdx.x;
    if (blockIdx.x < LSEQ) {   // RMSNorm row
        int l = blockIdx.x;
        float4v v = ((const float4v*)(x + (size_t)l * D_MODEL))[t];
        float ssq = v[0]*v[0] + v[1]*v[1] + v[2]*v[2] + v[3]*v[3];
        for (int o = 32; o > 0; o >>= 1) ssq += __shfl_down(ssq, o);
        __shared__ float part[4];
        int lane = t & 63, wid = t >> 6;
        if (lane == 0) part[wid] = ssq;
        __syncthreads();
        float tot = part[0] + part[1] + part[2] + part[3];
        float sc = rsqrtf(tot * (1.0f / D_MODEL) + 1e-5f);
        float4v nv = ((const float4v*)nw)[t];
        bf16* op = xn + (size_t)l * D_MODEL + t * 4;
        op[0] = f2b(v[0] * sc * nv[0]);
        op[1] = f2b(v[1] * sc * nv[1]);
        op[2] = f2b(v[2] * sc * nv[2]);
        op[3] = f2b(v[3] * sc * nv[3]);
        return;
    }
    int i4 = (blockIdx.x - LSEQ) * 256 + t;
    if (i4 >= NCAST4) return;
    const float* src; bf16* dst; int base;
    if (i4 < N1 / 4)                { src = w_in;  dst = o_in;  base = 0; }
    else if (i4 < (N1 + N2) / 4)    { src = w_out; dst = o_out; base = N1 / 4; }
    else if (i4 < (N1+N2+N3) / 4)   { src = w_xp;  dst = o_xp;  base = (N1+N2) / 4; }
    else                            { src = w_dt;  dst = o_dt;  base = (N1+N2+N3) / 4; }
    int j = i4 - base;
    float4v v = ((const float4v*)src)[j];
    bf16* o = dst + j * 4;
    o[0] = f2b(v[0]); o[1] = f2b(v[1]); o[2] = f2b(v[2]); o[3] = f2b(v[3]);
}

// ---- fast NT GEMM: 512 threads / 8 waves, wave tile 32x64, BK=64, dbuf LDS ---
// C[M,N] = A[M,K]*B[N,K]^T. Tiles 128x128. kLen%64==0.
// LDS physical 16B-chunk = logical chunk ^ (row&7) -> conflict-free stage+read.
// MODE 0: outB = bf16(acc)                       (xz)
// MODE 2: outB = bf16(softplus(acc+bias[n]))     (delta)
// MODE 5: outB[z-slice] = bf16(acc)  bf16 split-K partials (x-proj, out-proj)
template <int MODE>
__global__ __launch_bounds__(512)
void gemm_fast(const bf16* __restrict__ Ab, const bf16* __restrict__ Bb,
               int M, int N, int K, int kLen,
               float* __restrict__ outF, bf16* __restrict__ outB,
               const float* __restrict__ bias) {
    __shared__ short As[2][128 * 64];   // 16 KB per buffer
    __shared__ short Bs[2][128 * 64];
    const short* Ap = (const short*)Ab;
    const short* Bp = (const short*)Bb;

    int t = threadIdx.x;
    int lane = t & 63, wid = t >> 6;            // 8 waves
    int mBase = blockIdx.y * 128, nBase = blockIdx.x * 128;
    int kBase = blockIdx.z * kLen;
    int wm = 32 * (wid >> 1), wn = 64 * (wid & 1);   // wave tile 32x64
    int lr = lane & 15, quad = lane >> 4;

    // staging: wave wid owns rows [16*wid, 16*wid+16); 2 instrs of 8 rows each.
    int srow = 16 * wid + (lane >> 3);
    int cg2 = (lane & 7) ^ (lane >> 3);         // global chunk for phys chunk lane&7
    const short* gA = Ap + (size_t)(mBase + srow) * K + cg2 * 8;
    const short* gB = Bp + (size_t)(nBase + srow) * K + cg2 * 8;

    float4v acc[2][4] = {};

    // prologue: stage first K-slab into buf 0
    #pragma unroll
    for (int g = 0; g < 2; ++g) {
        GLOAD_LDS16(gA + (size_t)g * 8 * K + kBase, &As[0][(16 * wid + g * 8) * 64]);
        GLOAD_LDS16(gB + (size_t)g * 8 * K + kBase, &Bs[0][(16 * wid + g * 8) * 64]);
    }

    int p = 0;
    for (int kt = kBase; kt < kBase + kLen; kt += 64, p ^= 1) {
        __syncthreads();   // drains buf[p] loads; all waves past buf[p^1] reads
        if (kt + 64 < kBase + kLen) {
            int kn = kt + 64, q = p ^ 1;
            #pragma unroll
            for (int g = 0; g < 2; ++g) {
                GLOAD_LDS16(gA + (size_t)g * 8 * K + kn, &As[q][(16 * wid + g * 8) * 64]);
                GLOAD_LDS16(gB + (size_t)g * 8 * K + kn, &Bs[q][(16 * wid + g * 8) * 64]);
            }
        }
        #pragma unroll
        for (int s = 0; s < 2; ++s) {
            short8 af[2], bfr[4];
            #pragma unroll
            for (int i = 0; i < 2; ++i) {
                int row = wm + i * 16 + lr;
                af[i] = *(const short8*)&As[p][row * 64 + (((s * 4 + quad) ^ (lr & 7)) * 8)];
            }
            #pragma unroll
            for (int j = 0; j < 4; ++j) {
                int row = wn + j * 16 + lr;
                bfr[j] = *(const short8*)&Bs[p][row * 64 + (((s * 4 + quad) ^ (lr & 7)) * 8)];
            }
            #pragma unroll
            for (int i = 0; i < 2; ++i)
                #pragma unroll
                for (int j = 0; j < 4; ++j)
                    acc[i][j] = __builtin_amdgcn_mfma_f32_16x16x32_bf16(af[i], bfr[j], acc[i][j], 0, 0, 0);
        }
    }

    #pragma unroll
    for (int i = 0; i < 2; ++i) {
        #pragma unroll
        for (int j = 0; j < 4; ++j) {
            #pragma unroll
            for (int r = 0; r < 4; ++r) {
                int gm = mBase + wm + i * 16 + quad * 4 + r;
                int gn = nBase + wn + j * 16 + lr;
                float v = acc[i][j][r];
                if (MODE == 0) {
                    outB[(size_t)gm * N + gn] = f2b(v);
                } else if (MODE == 2) {
                    v += bias[gn];
                    v = (v > 20.0f) ? v : log1pf(__expf(v));
                    outB[(size_t)gm * N + gn] = f2b(v);
                } else {  // MODE 5: bf16 split-K partials
                    outB[((size_t)blockIdx.z * M + gm) * N + gn] = f2b(v);
                }
            }
        }
    }
}

// --------------- x_proj reduce: dbc = sum_z bf16 part, + dt bf16 cast ---------
__global__ __launch_bounds__(128)
void reduce_xproj(const bf16* __restrict__ part, float* __restrict__ dbc,
                  bf16* __restrict__ dtb) {
    int m = blockIdx.x, j = threadIdx.x;
    if (j >= 96) return;
    float v = 0.0f;
    #pragma unroll
    for (int z = 0; z < KSPL_X; ++z)
        v += b2f(part[((size_t)z * LSEQ + m) * 128 + j]);
    dbc[(size_t)m * 96 + j] = v;
    if (j < DT_RANK) dtb[(size_t)m * DT_RANK + j] = f2b(v);
}

// --------- out reduce: d_out = sum_z bf16 part + x (residual fused) -----------
__global__ __launch_bounds__(256)
void reduce_out(const bf16* __restrict__ part, const float* __restrict__ x,
                float* __restrict__ out) {
    int i = blockIdx.x * 256 + threadIdx.x;   // float4 over M*N/4
    const size_t MN = (size_t)LSEQ * D_MODEL;
    float a0 = 0, a1 = 0, a2 = 0, a3 = 0;
    #pragma unroll
    for (int z = 0; z < KSPL_O; ++z) {
        short4v b = *(const short4v*)((const short*)part + z * MN + (size_t)i * 4);
        a0 += us2f((unsigned short)b[0]);
        a1 += us2f((unsigned short)b[1]);
        a2 += us2f((unsigned short)b[2]);
        a3 += us2f((unsigned short)b[3]);
    }
    float4v xv = ((const float4v*)x)[i];
    float4v o = {a0 + xv[0], a1 + xv[1], a2 + xv[2], a3 + xv[3]};
    ((float4v*)out)[i] = o;
}

// ------------- depthwise causal conv+SiLU, 2 channels x 4 timesteps/thread ----
__global__ void conv_kernel(const bf16* __restrict__ xz, const float* __restrict__ cw,
                            const float* __restrict__ cb, bf16* __restrict__ xsb) {
    int idx = blockIdx.x * 256 + threadIdx.x;   // over (LSEQ/4)*(D_INNER/2)
    int c = (idx & (D_INNER / 2 - 1)) * 2;
    int l0 = (idx >> 10) * 4;
    float4v wA = ((const float4v*)cw)[c];       // cw row c: 4 floats
    float4v wB = ((const float4v*)cw)[c + 1];
    float bA = cb[c], bB = cb[c + 1];
    const unsigned int* col = (const unsigned int*)((const unsigned short*)xz + c);
    float vA[7], vB[7];
    #pragma unroll
    for (int j = 0; j < 7; ++j) {
        int l = l0 - 3 + j;
        if (l >= 0) {
            unsigned int u = col[(size_t)l * D_INNER];   // 2 bf16 = 4B, stride 2*D_INNER shorts
            vA[j] = us2f((unsigned short)(u & 0xffff));
            vB[j] = us2f((unsigned short)(u >> 16));
        } else { vA[j] = 0.0f; vB[j] = 0.0f; }
    }
    #pragma unroll
    for (int j = 0; j < 4; ++j) {
        float aA = bA + vA[j]*wA[0] + vA[j+1]*wA[1] + vA[j+2]*wA[2] + vA[j+3]*wA[3];
        float aB = bB + vB[j]*wB[0] + vB[j+1]*wB[1] + vB[j+2]*wB[2] + vB[j+3]*wB[3];
        float sA = aA * (1.0f / (1.0f + __expf(-aA)));
        float sB = aB * (1.0f / (1.0f + __expf(-aB)));
        unsigned int o = (unsigned int)f2us(sA) | ((unsigned int)f2us(sB) << 16);
        *(unsigned int*)((unsigned short*)xsb + (size_t)(l0 + j) * D_INNER + c) = o;
    }
}

// ------------------------------- chunked selective scan, states in registers --
// P/S/Hinit in bf16: chunk-compose is a contraction (p<1), errors decay.
template <int PASS>
__global__ __launch_bounds__(256)
void scan2(const bf16* __restrict__ delta, const bf16* __restrict__ xsb,
           const float* __restrict__ dbc, const bf16* __restrict__ xz,
           const float* __restrict__ A_log, const float* __restrict__ Dw,
           const bf16* __restrict__ Hinit,
           bf16* __restrict__ P, bf16* __restrict__ S, bf16* __restrict__ yg) {
    __shared__ float bc[CHUNK][32];   // [l][B(16)|C(16)]
    int t = threadIdx.x;
    int d = blockIdx.x * 256 + t;
    int c = blockIdx.y;
    int l0 = c * CHUNK;

    {   // stage B,C for this chunk: 32 rows x 32 floats = 4 KB
        int row = t >> 3, col = (t & 7) * 4;
        *(float4v*)&bc[row][col] = *(const float4v*)&dbc[(size_t)(l0 + row) * 96 + 64 + col];
    }
    __syncthreads();

    float A[16], h[16], pr[16];
    #pragma unroll
    for (int n = 0; n < 16; ++n) A[n] = -__expf(A_log[(size_t)d * 16 + n]);
    if (PASS == 0) {
        #pragma unroll
        for (int n = 0; n < 16; ++n) { h[n] = 0.0f; pr[n] = 1.0f; }
    } else {
        ld_bf16x16(Hinit + (size_t)c * DN + (size_t)d * 16, h);
    }
    float Dd = (PASS == 1) ? Dw[d] : 0.0f;

    for (int i = 0; i < CHUNK; ++i) {
        int l = l0 + i;
        float dv = b2f(delta[(size_t)l * D_INNER + d]);
        float xv = b2f(xsb[(size_t)l * D_INNER + d]);
        float u = dv * xv;
        #pragma unroll
        for (int n = 0; n < 16; ++n) {
            float a = __expf(dv * A[n]);
            h[n] = fmaf(a, h[n], bc[i][n] * u);
            if (PASS == 0) pr[n] *= a;
        }
        if (PASS == 1) {
            float y = xv * Dd;
            #pragma unroll
            for (int n = 0; n < 16; ++n) y = fmaf(h[n], bc[i][16 + n], y);
            float r = b2f(xz[(size_t)l * (2 * D_INNER) + D_INNER + d]);
            float g = r * (1.0f / (1.0f + __expf(-r)));
            yg[(size_t)l * D_INNER + d] = f2b(y * g);
        }
    }
    if (PASS == 0) {
        st_bf16x16(P + (size_t)c * DN + (size_t)d * 16, pr);
        st_bf16x16(S + (size_t)c * DN + (size_t)d * 16, h);
    }
}

// Sequential compose over chunks: h_init[c+1] = P[c]*h_init[c] + S[c].  (bf16 io)
__global__ __launch_bounds__(256)
void scan_mid(const bf16* __restrict__ P, const bf16* __restrict__ S,
              bf16* __restrict__ Hinit) {
    int idx = blockIdx.x * 256 + threadIdx.x;   // over DN
    float h = 0.0f;
    for (int c0 = 0; c0 < NCHUNK; c0 += 8) {
        float p[8], s[8];
        #pragma unroll
        for (int j = 0; j < 8; ++j) {
            p[j] = b2f(P[(size_t)(c0 + j) * DN + idx]);
            s[j] = b2f(S[(size_t)(c0 + j) * DN + idx]);
        }
        #pragma unroll
        for (int j = 0; j < 8; ++j) {
            Hinit[(size_t)(c0 + j) * DN + idx] = f2b(h);
            h = fmaf(p[j], h, s[j]);
        }
    }
}

// -------------------------------------------------------------- launcher ----
extern "C" void kernel_launch(void* const* d_in, const int* in_sizes, int n_in,
                              void* d_out, int out_size, void* d_ws, size_t ws_size,
                              hipStream_t stream) {
    const float* x       = (const float*)d_in[0];
    const float* W_in    = (const float*)d_in[1];
    const float* conv_w  = (const float*)d_in[2];
    const float* conv_b  = (const float*)d_in[3];
    const float* W_xproj = (const float*)d_in[4];
    const float* W_dt    = (const float*)d_in[5];
    const float* b_dt    = (const float*)d_in[6];
    const float* A_log   = (const float*)d_in[7];
    const float* Dw      = (const float*)d_in[8];
    const float* W_out   = (const float*)d_in[9];
    const float* norm_w  = (const float*)d_in[10];

    char* w = (char*)d_ws;
    bf16* W_in_b    = (bf16*)w; w += (size_t)2 * D_INNER * D_MODEL * 2;   // 8 MB
    bf16* W_out_b   = (bf16*)w; w += (size_t)D_MODEL * D_INNER * 2;       // 4 MB
    bf16* W_xproj_b = (bf16*)w; w += (size_t)128 * D_INNER * 2;           // 512 KB (rows 96..127 pad)
    bf16* W_dt_b    = (bf16*)w; w += (size_t)D_INNER * DT_RANK * 2;       // 256 KB
    char* reuse0 = w;   // aliased by out_part after scan
    bf16* xn        = (bf16*)w; w += (size_t)LSEQ * D_MODEL * 2;          // 4 MB
    bf16* xz        = (bf16*)w; w += (size_t)LSEQ * 2 * D_INNER * 2;      // 16 MB
    bf16* xsb       = (bf16*)w; w += (size_t)LSEQ * D_INNER * 2;          // 8 MB
    bf16* delta     = (bf16*)w; w += (size_t)LSEQ * D_INNER * 2;          // 8 MB  (36 MB pool)
    float* dbc      = (float*)w; w += (size_t)LSEQ * 96 * 4;              // 768 KB
    bf16* dtb       = (bf16*)w; w += (size_t)LSEQ * DT_RANK * 2;          // 256 KB
    bf16* yg        = (bf16*)w; w += (size_t)LSEQ * D_INNER * 2;          // 8 MB
    bf16* Pbuf      = (bf16*)w; w += (size_t)NCHUNK * DN * 2;             // 4 MB
    bf16* Sbuf      = (bf16*)w; w += (size_t)NCHUNK * DN * 2;             // 4 MB
    bf16* Hinit     = (bf16*)w; w += (size_t)NCHUNK * DN * 2;             // 4 MB
    bf16* xp_part   = (bf16*)w; w += (size_t)KSPL_X * LSEQ * 128 * 2;     // 8 MB
    bf16* out_part  = (bf16*)reuse0;   // 16 MB bf16, aliases xn/xz (dead by then)

    prep_kernel<<<LSEQ + (NCAST4 + 255) / 256, 256, 0, stream>>>(
        x, norm_w, xn, W_in, W_out, W_xproj, W_dt, W_in_b, W_out_b, W_xproj_b, W_dt_b);

    // in_proj: (2048 x 4096) = xn (2048x1024) * W_in^T
    gemm_fast<0><<<dim3(4096 / 128, 2048 / 128, 1), 512, 0, stream>>>(
        xn, W_in_b, 2048, 4096, 1024, 1024, nullptr, xz, nullptr);

    conv_kernel<<<(LSEQ / 4) * (D_INNER / 2) / 256, 256, 0, stream>>>(xz, conv_w, conv_b, xsb);

    // x_proj: (2048 x 96) = xsb (2048x2048) * W_xproj^T, split-K=16, bf16 partials
    gemm_fast<5><<<dim3(1, 2048 / 128, KSPL_X), 512, 0, stream>>>(
        xsb, W_xproj_b, 2048, 128, 2048, 2048 / KSPL_X, nullptr, xp_part, nullptr);
    reduce_xproj<<<LSEQ, 128, 0, stream>>>(xp_part, dbc, dtb);

    // delta: (2048 x 2048) = dtb (2048x64) * W_dt^T, softplus+bias epilogue
    gemm_fast<2><<<dim3(2048 / 128, 2048 / 128, 1), 512, 0, stream>>>(
        dtb, W_dt_b, 2048, 2048, 64, 64, nullptr, delta, b_dt);

    dim3 sgrid(D_INNER / 256, NCHUNK);
    scan2<0><<<sgrid, 256, 0, stream>>>(delta, xsb, dbc, xz, A_log, Dw,
                                        nullptr, Pbuf, Sbuf, nullptr);
    scan_mid<<<DN / 256, 256, 0, stream>>>(Pbuf, Sbuf, Hinit);
    scan2<1><<<sgrid, 256, 0, stream>>>(delta, xsb, dbc, xz, A_log, Dw,
                                        Hinit, nullptr, nullptr, yg);

    // out_proj: (2048 x 1024) = yg (2048x2048) * W_out^T, split-K=4, bf16 partials
    gemm_fast<5><<<dim3(1024 / 128, 2048 / 128, KSPL_O), 512, 0, stream>>>(
        yg, W_out_b, 2048, 1024, 2048, 2048 / KSPL_O, nullptr, out_part, nullptr);
    reduce_out<<<LSEQ * D_MODEL / 4 / 256, 256, 0, stream>>>(out_part, x, (float*)d_out);
}